// Round 7
// baseline (199.996 us; speedup 1.0000x reference)
//
#include <hip/hip_runtime.h>

#define N_NODES 50000
#define N_EDGES 800000
#define NE4 (N_EDGES / 4)
#define NMASKW 1568          // ceil(50000/32)=1563, padded
#define MAXN1 192            // LDS accumulator rows in fusedD (deg(node1)~16, margin 12x)
#define MAXDEG 512           // per-node in-degree cap in layer12 (Poisson(16), margin ~30x)

__device__ __forceinline__ float lrelu(float v) { return v >= 0.f ? v : 0.01f * v; }
__device__ __forceinline__ bool mtest(const unsigned int* m, int i) {
    return (m[i >> 5] >> (i & 31)) & 1u;
}

// ---- scanA: agg0[d] += x[s] (unfiltered); f1 bits + e1src for dst==1 ----
__global__ void scanA_k(const int4* __restrict__ src4, const int4* __restrict__ dst4,
                        const float* __restrict__ x, unsigned int* __restrict__ f1m,
                        int* __restrict__ e1src, int* __restrict__ cntE1,
                        float* __restrict__ agg0) {
    int t = blockIdx.x * blockDim.x + threadIdx.x;
    if (t >= NE4) return;
    int4 s = src4[t];
    int4 d = dst4[t];
    atomicAdd(&agg0[d.x], x[s.x]);
    atomicAdd(&agg0[d.y], x[s.y]);
    atomicAdd(&agg0[d.z], x[s.z]);
    atomicAdd(&agg0[d.w], x[s.w]);
    if (d.x == 1) { atomicOr(&f1m[s.x >> 5], 1u << (s.x & 31)); e1src[atomicAdd(cntE1, 1)] = s.x; }
    if (d.y == 1) { atomicOr(&f1m[s.y >> 5], 1u << (s.y & 31)); e1src[atomicAdd(cntE1, 1)] = s.y; }
    if (d.z == 1) { atomicOr(&f1m[s.z >> 5], 1u << (s.z & 31)); e1src[atomicAdd(cntE1, 1)] = s.z; }
    if (d.w == 1) { atomicOr(&f1m[s.w >> 5], 1u << (s.w & 31)); e1src[atomicAdd(cntE1, 1)] = s.w; }
}

// ---- scanB: edges with f1[dst] -> eD list + f2 bits (f1 mask staged in LDS) ----
__global__ void scanB_k(const int4* __restrict__ dst4, const int* __restrict__ src,
                        const unsigned int* __restrict__ f1m, unsigned int* __restrict__ f2m,
                        int2* __restrict__ eD, int* __restrict__ cntD) {
    __shared__ unsigned int m[NMASKW];
    for (int k = threadIdx.x; k < NMASKW; k += blockDim.x) m[k] = f1m[k];
    __syncthreads();
    int t = blockIdx.x * blockDim.x + threadIdx.x;
    if (t >= NE4) return;
    int4 d = dst4[t];
    int base = t * 4;
#define DO_E(dd, off) \
    if (mtest(m, dd)) { int s = src[base + off]; atomicOr(&f2m[s >> 5], 1u << (s & 31)); \
                        eD[atomicAdd(cntD, 1)] = make_int2(s, dd); }
    DO_E(d.x, 0) DO_E(d.y, 1) DO_E(d.z, 2) DO_E(d.w, 3)
#undef DO_E
}

// ---- scanC + compact fused (both depend only on completed f1/f2):
//      edges with f2[dst] -> eC list;  nodes: list1/pos1 (f1), list2 (f2) ----
__global__ void scanC_k(const int4* __restrict__ dst4, const int* __restrict__ src,
                        const unsigned int* __restrict__ f1m, const unsigned int* __restrict__ f2m,
                        int2* __restrict__ eC, int* __restrict__ cntC,
                        int* __restrict__ list1, int* __restrict__ cnt1, int* __restrict__ pos1,
                        int* __restrict__ list2, int* __restrict__ cnt2) {
    __shared__ unsigned int m1[NMASKW];
    __shared__ unsigned int m2[NMASKW];
    for (int k = threadIdx.x; k < NMASKW; k += blockDim.x) { m1[k] = f1m[k]; m2[k] = f2m[k]; }
    __syncthreads();
    int t = blockIdx.x * blockDim.x + threadIdx.x;
    if (t < NE4) {
        int4 d = dst4[t];
        int base = t * 4;
        if (mtest(m2, d.x)) eC[atomicAdd(cntC, 1)] = make_int2(src[base + 0], d.x);
        if (mtest(m2, d.y)) eC[atomicAdd(cntC, 1)] = make_int2(src[base + 1], d.y);
        if (mtest(m2, d.z)) eC[atomicAdd(cntC, 1)] = make_int2(src[base + 2], d.z);
        if (mtest(m2, d.w)) eC[atomicAdd(cntC, 1)] = make_int2(src[base + 3], d.w);
    }
    if (t < N_NODES) {
        if (mtest(m1, t)) { int p = atomicAdd(cnt1, 1); list1[p] = t; pos1[t] = p; }
        if (mtest(m2, t)) { list2[atomicAdd(cnt2, 1)] = t; }
    }
}

// ---- layer12: per N2-node block: gather in-edge agg0 values from eC, apply layer0
//      linear+lrelu, aggregate, then h1 = lrelu(.@W1+b1), t2 = h1@W2 ----
__global__ __launch_bounds__(128) void layer12_k(const int2* __restrict__ eC,
                                                 const int* __restrict__ cntC,
                                                 const float* __restrict__ agg0,
                                                 const int* __restrict__ list2,
                                                 const int* __restrict__ cnt2,
                                                 const float* __restrict__ W0,
                                                 const float* __restrict__ b0,
                                                 const float* __restrict__ W1,
                                                 const float* __restrict__ b1,
                                                 const float* __restrict__ W2,
                                                 float* __restrict__ t2) {
    __shared__ float xs[MAXDEG];
    __shared__ int nxs;
    __shared__ float rowA[64];
    __shared__ float rowH[128];
    int tid = threadIdx.x;
    int cC = *cntC, c2 = *cnt2;
    for (int idx = blockIdx.x; idx < c2; idx += gridDim.x) {
        int i = list2[idx];
        __syncthreads();                      // protect xs/nxs/rowA/rowH reuse
        if (tid == 0) nxs = 0;
        __syncthreads();
        for (int k = tid; k < cC; k += 128) {
            int2 e = eC[k];
            if (e.y == i) {
                int p = atomicAdd(&nxs, 1);
                if (p < MAXDEG) xs[p] = agg0[e.x];
            }
        }
        __syncthreads();
        int deg = nxs < MAXDEG ? nxs : MAXDEG;
        if (tid < 64) {
            float w = W0[tid], b = b0[tid], s = 0.f;
            for (int k = 0; k < deg; ++k) s += lrelu(xs[k] * w + b);
            rowA[tid] = s;
        }
        __syncthreads();
        float acc = b1[tid];
#pragma unroll
        for (int k = 0; k < 64; ++k) acc += rowA[k] * W1[k * 128 + tid];
        rowH[tid] = lrelu(acc);
        __syncthreads();
        if (tid < 64) {
            float a2 = 0.f;
#pragma unroll
            for (int k = 0; k < 128; ++k) a2 += rowH[k] * W2[k * 64 + tid];
            t2[(size_t)i * 64 + tid] = a2;
        }
    }
}

// ---- fusedD: layer-2 agg (LDS acc over eD) + layer-3 linear + final sum, 1 block ----
__global__ __launch_bounds__(256) void fusedD_k(const int2* __restrict__ eD, const int* __restrict__ cntD,
                                                const float* __restrict__ t2, const int* __restrict__ pos1,
                                                const int* __restrict__ cnt1, const int* __restrict__ e1src,
                                                const int* __restrict__ cntE1, const float* __restrict__ b2,
                                                const float* __restrict__ W3, const float* __restrict__ b3,
                                                float* __restrict__ out) {
    __shared__ float acc[MAXN1 * 64];   // 48 KB
    __shared__ float t3s[MAXN1];
    int tid = threadIdx.x;
    int c1 = *cnt1, cD = *cntD, cE = *cntE1;
    for (int k = tid; k < c1 * 64; k += 256) acc[k] = 0.f;
    __syncthreads();
    int j = tid & 63, widx = tid >> 6;           // 4 waves
    for (int idx = widx; idx < cD; idx += 4) {
        int2 e = eD[idx];
        float v = t2[(size_t)e.x * 64 + j];
        atomicAdd(&acc[pos1[e.y] * 64 + j], v);
    }
    __syncthreads();
    for (int slot = widx; slot < c1; slot += 4) {
        float v = lrelu(acc[slot * 64 + j] + b2[j]) * W3[j];
        for (int off = 32; off > 0; off >>= 1) v += __shfl_down(v, off, 64);
        if (j == 0) t3s[slot] = v;
    }
    __syncthreads();
    if (tid < 64) {
        float s = 0.f;
        for (int k = tid; k < cE; k += 64) s += t3s[pos1[e1src[k]]];
        for (int off = 32; off > 0; off >>= 1) s += __shfl_down(s, off, 64);
        if (tid == 0) out[0] = lrelu(s + b3[0]);
    }
}

extern "C" void kernel_launch(void* const* d_in, const int* in_sizes, int n_in,
                              void* d_out, int out_size, void* d_ws, size_t ws_size,
                              hipStream_t stream) {
    const float* in_feat = (const float*)d_in[0];
    const int*   src     = (const int*)d_in[1];
    const int*   dst     = (const int*)d_in[2];
    const float* W0 = (const float*)d_in[3];  const float* b0 = (const float*)d_in[4];
    const float* W1 = (const float*)d_in[5];  const float* b1 = (const float*)d_in[6];
    const float* W2 = (const float*)d_in[7];  const float* b2 = (const float*)d_in[8];
    const float* W3 = (const float*)d_in[9];  const float* b3 = (const float*)d_in[10];
    float* out = (float*)d_out;
    const int4* src4 = (const int4*)src;
    const int4* dst4 = (const int4*)dst;

    // ---- workspace: zeroed prefix first ----
    char* base = (char*)d_ws;
    size_t off = 0;
    auto take = [&](size_t bytes) { char* p = base + off; off += (bytes + 255) & ~(size_t)255; return p; };
    unsigned int* f1m = (unsigned int*)take(NMASKW * 4);      // zeroed
    unsigned int* f2m = (unsigned int*)take(NMASKW * 4);      // zeroed
    int* cntE1 = (int*)take(4);                               // zeroed
    int* cntD  = (int*)take(4);                               // zeroed
    int* cntC  = (int*)take(4);                               // zeroed
    int* cnt1  = (int*)take(4);                               // zeroed
    int* cnt2  = (int*)take(4);                               // zeroed
    float* agg0 = (float*)take((size_t)N_NODES * 4);          // zeroed
    size_t zero_bytes = off;
    float* t2   = (float*)take((size_t)N_NODES * 64 * 4);
    int*  e1src = (int*)take((size_t)N_NODES * 4);
    int2* eD    = (int2*)take((size_t)N_EDGES * 8);
    int2* eC    = (int2*)take((size_t)N_EDGES * 8);
    int*  list1 = (int*)take((size_t)N_NODES * 4);
    int*  list2 = (int*)take((size_t)N_NODES * 4);
    int*  pos1  = (int*)take((size_t)N_NODES * 4);

    const int SB = (NE4 + 255) / 256;   // 782 blocks

    hipMemsetAsync(base, 0, zero_bytes, stream);                                   // ~213 KB
    scanA_k<<<SB, 256, 0, stream>>>(src4, dst4, in_feat, f1m, e1src, cntE1, agg0); // agg0+f1
    scanB_k<<<SB, 256, 0, stream>>>(dst4, src, f1m, f2m, eD, cntD);                // f2 + eD
    scanC_k<<<SB, 256, 0, stream>>>(dst4, src, f1m, f2m, eC, cntC,
                                    list1, cnt1, pos1, list2, cnt2);               // eC + lists
    layer12_k<<<256, 128, 0, stream>>>(eC, cntC, agg0, list2, cnt2,
                                       W0, b0, W1, b1, W2, t2);                    // layers 0-2 linear
    fusedD_k<<<1, 256, 0, stream>>>(eD, cntD, t2, pos1, cnt1, e1src, cntE1,
                                    b2, W3, b3, out);                              // tail
}